// Round 18
// baseline (125.480 us; speedup 1.0000x reference)
//
#include <hip/hip_runtime.h>
#include <hip/hip_bf16.h>

#define HEADS 16
#define DH 64
#define DIM 1024
#define SEQ 2048
#define BATCH 2
#define ROWS (BATCH*SEQ)      // 4096
#define NQKV (3*DIM)          // 3072
#define NKVT (SEQ/64)         // 32 kv tiles per bh
#define NSPLIT 4
#define QSCALE 0.18033688011112042f   // 0.125 * log2(e)
#define NBH (BATCH*HEADS)             // 32
#define NQROWS (NBH*SEQ)              // 65536

typedef __attribute__((ext_vector_type(8))) short bf16x8;
typedef __attribute__((ext_vector_type(4))) float f32x4;
typedef __attribute__((ext_vector_type(16))) float f32x16;
typedef __attribute__((ext_vector_type(4))) unsigned u32x4;
typedef __hip_bfloat16 bf16;

static __device__ __forceinline__ bf16 f2bf(float v){ return __float2bfloat16(v); }

// v_cvt_pk_bf16_f32: D.lo16 = bf16(S0), D.hi16 = bf16(S1)
static __device__ __forceinline__ unsigned cvtpk(float a, float b){
  unsigned r;
  asm("v_cvt_pk_bf16_f32 %0, %1, %2" : "=v"(r) : "v"(a), "v"(b));
  return r;
}

static __device__ __forceinline__ void gload16(const void* g, void* lds){
  __builtin_amdgcn_global_load_lds((const __attribute__((address_space(1))) void*)g,
                                   (__attribute__((address_space(3))) void*)lds, 16, 0, 0);
}

// ---------------- prep: LN (blocks 0..4095) + w_qkv^T (next 768) + w_out^T (next 256) --
__global__ __launch_bounds__(256) void prep_kernel(
    const float* __restrict__ x, const float* __restrict__ gamma,
    const float* __restrict__ beta, bf16* __restrict__ xn,
    const float* __restrict__ w_qkv, bf16* __restrict__ wqt,
    const float* __restrict__ w_out, bf16* __restrict__ wot)
{
  __shared__ float red[8];
  __shared__ __align__(16) bf16 tt[64][72];
  int bid = blockIdx.x;
  int tid = threadIdx.x;
  if (bid < ROWS){
    int row = bid;
    float4 v = ((const float4*)(x + (size_t)row*DIM))[tid];
    float s  = v.x+v.y+v.z+v.w;
    float ss = v.x*v.x+v.y*v.y+v.z*v.z+v.w*v.w;
    #pragma unroll
    for (int m=1;m<64;m<<=1){ s += __shfl_xor(s,m); ss += __shfl_xor(ss,m); }
    int wid = tid>>6;
    if ((tid&63)==0){ red[wid]=s; red[4+wid]=ss; }
    __syncthreads();
    s  = red[0]+red[1]+red[2]+red[3];
    ss = red[4]+red[5]+red[6]+red[7];
    float mu  = s*(1.0f/DIM);
    float var = ss*(1.0f/DIM) - mu*mu;
    float inv = rsqrtf(var + 1e-5f);
    float4 g  = ((const float4*)gamma)[tid];
    float4 bb = ((const float4*)beta)[tid];
    __align__(8) bf16 o[4];
    o[0]=f2bf((v.x-mu)*inv*g.x+bb.x);
    o[1]=f2bf((v.y-mu)*inv*g.y+bb.y);
    o[2]=f2bf((v.z-mu)*inv*g.z+bb.z);
    o[3]=f2bf((v.w-mu)*inv*g.w+bb.w);
    *(uint2*)&xn[(size_t)row*DIM + tid*4] = *(const uint2*)o;
    return;
  }
  const float* in; bf16* out; int R, C, bx, by;
  if (bid < ROWS + 768){
    int idx = bid - ROWS; bx = idx % 48; by = idx / 48;
    in = w_qkv; out = wqt; R = DIM; C = NQKV;
  } else {
    int idx = bid - ROWS - 768; bx = idx % 16; by = idx / 16;
    in = w_out; out = wot; R = DIM; C = DIM;
  }
  int c0 = bx*64, r0 = by*64;
  int row = tid>>2;
  int cq  = (tid&3)*16;
  #pragma unroll
  for (int j=0;j<4;j++){
    float4 v = *(const float4*)&in[(size_t)(r0+row)*C + c0 + cq + j*4];
    tt[cq+j*4+0][row] = f2bf(v.x);
    tt[cq+j*4+1][row] = f2bf(v.y);
    tt[cq+j*4+2][row] = f2bf(v.z);
    tt[cq+j*4+3][row] = f2bf(v.w);
  }
  __syncthreads();
  int c = tid>>2; int rq = (tid&3)*16;
  uint4 u0 = *(const uint4*)&tt[c][rq];
  uint4 u1 = *(const uint4*)&tt[c][rq+8];
  *(uint4*)&out[(size_t)(c0+c)*R + r0 + rq]     = u0;
  *(uint4*)&out[(size_t)(c0+c)*R + r0 + rq + 8] = u1;
}

// ---------------- GEMM v5: BK=32, 3-buffer counted-vmcnt pipeline, XCD swizzle -------
template<int BM>
__global__ __launch_bounds__(256) void gemm_bt(
    const bf16* __restrict__ A, const bf16* __restrict__ Bt, int K, int mode,
    bf16* __restrict__ qb, bf16* __restrict__ kb, bf16* __restrict__ vtb,
    float* __restrict__ outf, const float* __restrict__ bias)
{
  constexpr int MT = (BM == 128) ? 4 : 2;
  constexpr int NT = (BM == 128) ? 4 : 2;
  __shared__ __align__(16) bf16 aL[3][BM*32];
  __shared__ __align__(16) bf16 bL[3][BM*32];
  int tid = threadIdx.x;
  int w = tid>>6, l = tid&63;
  int lr = l&15, lh = l>>4;
  int wr = w>>1, wc = w&1;
  // XCD-aware bijective swizzle (grid %8 == 0)
  int nbx = gridDim.x;
  int lin = blockIdx.y*nbx + blockIdx.x;
  int cpx = (nbx*gridDim.y) >> 3;
  int nl  = (lin & 7)*cpx + (lin >> 3);
  int bx = nl % nbx, by = nl / nbx;
  const bf16* Ab = A  + (size_t)(by*BM)*K;
  const bf16* Bb = Bt + (size_t)(bx*BM)*K;
  int srow = w*32 + (l>>2);
  int scol = ((l&3)*8) ^ (((l>>2)&3)<<3);         // pre-swizzled global column
  int frsw = (lr&3)<<3;
  int nt = K/32;

  f32x4 acc[MT][NT] = {};

  auto STAGE = [&](int buf, int k0){
    if constexpr (BM == 128){
      gload16(Ab + (size_t)(srow   )*K + k0 + scol, &aL[buf][w*1024      ]);
      gload16(Ab + (size_t)(srow+16)*K + k0 + scol, &aL[buf][w*1024 + 512]);
      gload16(Bb + (size_t)(srow   )*K + k0 + scol, &bL[buf][w*1024      ]);
      gload16(Bb + (size_t)(srow+16)*K + k0 + scol, &bL[buf][w*1024 + 512]);
    } else {
      gload16(Ab + (size_t)(tid>>2)*K + k0 + scol, &aL[buf][w*512]);
      gload16(Bb + (size_t)(tid>>2)*K + k0 + scol, &bL[buf][w*512]);
    }
  };

  auto COMPUTE = [&](int buf){
    bf16x8 af[MT], bfr[NT];
    #pragma unroll
    for (int m=0;m<MT;m++)
      af[m]  = *(const bf16x8*)&aL[buf][(wr*(MT*16) + m*16 + lr)*32 + ((lh*8) ^ frsw)];
    #pragma unroll
    for (int n=0;n<NT;n++)
      bfr[n] = *(const bf16x8*)&bL[buf][(wc*(NT*16) + n*16 + lr)*32 + ((lh*8) ^ frsw)];
    #pragma unroll
    for (int m=0;m<MT;m++)
      #pragma unroll
      for (int n=0;n<NT;n++)
        acc[m][n] = __builtin_amdgcn_mfma_f32_16x16x32_bf16(af[m], bfr[n], acc[m][n], 0,0,0);
  };

  STAGE(0, 0);
  STAGE(1, 32);
  int cur = 0;
  for (int t=0; t<nt-1; t++){
    if constexpr (BM == 128) asm volatile("s_waitcnt vmcnt(4)" ::: "memory");
    else                     asm volatile("s_waitcnt vmcnt(2)" ::: "memory");
    __builtin_amdgcn_s_barrier();
    __builtin_amdgcn_sched_barrier(0);
    int s2 = cur + 2; if (s2 >= 3) s2 -= 3;
    if (t+2 < nt) STAGE(s2, (t+2)*32);
    COMPUTE(cur);
    cur = (cur == 2) ? 0 : cur + 1;
  }
  asm volatile("s_waitcnt vmcnt(0)" ::: "memory");
  __builtin_amdgcn_s_barrier();
  __builtin_amdgcn_sched_barrier(0);
  COMPUTE(cur);

  int rb = by*BM + wr*(MT*16), cb = bx*BM + wc*(NT*16);
  if (mode == 1){
    #pragma unroll
    for (int m=0;m<MT;m++)
      #pragma unroll
      for (int n=0;n<NT;n++)
        #pragma unroll
        for (int reg=0;reg<4;reg++){
          int r = rb + m*16 + lh*4 + reg;
          int c = cb + n*16 + lr;
          outf[(size_t)r*DIM + c] = acc[m][n][reg] + bias[c];
        }
  } else if (bx < 8){            // ---- Q: scaled (log2 domain), row-major [bh][n][d]
    int b = rb >> 11;
    int nn0 = rb & 2047;
    #pragma unroll
    for (int m=0;m<MT;m++)
      #pragma unroll
      for (int n=0;n<NT;n++)
        #pragma unroll
        for (int reg=0;reg<4;reg++){
          int nn = nn0 + m*16 + lh*4 + reg;
          int c  = cb + n*16 + lr;
          int hh = c >> 6, dd = c & 63;
          qb[((size_t)(b*HEADS + hh)*SEQ + nn)*DH + dd] = f2bf(acc[m][n][reg]*QSCALE);
        }
  } else if (bx < 16){           // ---- K: 64x64 tiles, swizzled in global
    int b = rb >> 11;
    int kvt = (rb & 2047) >> 6;
    int hh0 = ((cb - 1024) >> 6);
    #pragma unroll
    for (int m=0;m<MT;m++)
      #pragma unroll
      for (int reg=0;reg<4;reg++){
        int kvi = m*16 + lh*4 + reg;
        int sw  = (kvi&7)<<3;
        #pragma unroll
        for (int n=0;n<NT;n++){
          int dd = n*16 + lr;
          kb[((size_t)(b*HEADS + hh0)*NKVT + kvt)*4096 + kvi*64 + (dd ^ sw)] = f2bf(acc[m][n][reg]);
        }
      }
  } else {                       // ---- V: transpose in LDS, coalesced 16B stores
    __syncthreads();
    bf16* tl = (w < 2 ? (bf16*)aL : (bf16*)bL) + (w&1)*4096;
    int b   = rb >> 11;
    int kvt = (rb & 2047) >> 6;
    int hh  = (cb - 2048) >> 6;
    #pragma unroll
    for (int n=0;n<NT;n++){
      int dd = n*16 + lr;
      int sw = (dd&7)<<3;
      #pragma unroll
      for (int m=0;m<MT;m++)
        #pragma unroll
        for (int reg=0;reg<4;reg++)
          tl[dd*64 + ((m*16 + lh*4 + reg) ^ sw)] = f2bf(acc[m][n][reg]);
    }
    __syncthreads();
    size_t gb = ((size_t)(b*HEADS + hh)*NKVT + kvt)*4096;
    #pragma unroll
    for (int j=0;j<8;j++)
      *(uint4*)&vtb[gb + j*512 + l*8] = *(const uint4*)&tl[j*512 + l*8];
  }
}

// ---------------- flash attention v11: 8-wave blocks, NSPLIT=4 -> 32 waves/CU --------
// Same per-wave structure as v10; grid 8x32x4 = 1024 blocks = 4 resident blocks/CU.
__global__ __launch_bounds__(512,4) void attn_part(
    const bf16* __restrict__ qb, const bf16* __restrict__ kb,
    const bf16* __restrict__ vtb,
    bf16* __restrict__ Opart, float* __restrict__ Mpart, float* __restrict__ Spart)
{
  __shared__ __align__(16) bf16 Kl[2][4096];
  __shared__ __align__(16) bf16 Vl[2][4096];
  int tid = threadIdx.x;
  int w = tid>>6, l = tid&63;      // w in 0..7
  int q5 = l & 31;
  int hi = l >> 5;
  int swz = (q5&7)<<3;
  // XCD swizzle: grid 8x32x4 = 1024 blocks; each XCD owns 16 full (bh,sp) groups
  int lin = (blockIdx.z*gridDim.y + blockIdx.y)*gridDim.x + blockIdx.x;
  int nl  = (lin & 7)*128 + (lin >> 3);
  int bqx = nl & 7;
  int bh  = (nl >> 3) & 31;
  int sp  = nl >> 8;
  int ts = sp*8, te = ts+8;
  const bf16* Q  = qb  + (size_t)bh*SEQ*DH;
  const bf16* Kt = kb  + (size_t)bh*NKVT*4096;
  const bf16* Vt = vtb + (size_t)bh*NKVT*4096;
  int q0w = bqx*256 + w*32;   // this wave's 32 Q rows

  int co[4];
  #pragma unroll
  for (int st=0;st<4;st++) co[st] = (st*16 + hi*8) ^ swz;
  int r0 = q5*64, r1 = r0 + 2048;

  bf16x8 qf[4];
  #pragma unroll
  for (int st=0;st<4;st++)
    qf[st] = *(const bf16x8*)&Q[(size_t)(q0w + q5)*DH + st*16 + hi*8];

  bf16x8 vone;
  #pragma unroll
  for (int i=0;i<8;i++) vone[i] = (short)0x3f80;   // bf16 1.0

  f32x16 o0 = {}, o1 = {}, osum = {};  // d-tiles 0/1 and the ones-column row-sum
  float mrun = -3e38f;

  // prologue: 8 waves cooperatively stage tile ts (1 K-load + 1 V-load per wave)
  gload16(Kt + (size_t)ts*4096 + w*512 + l*8, &Kl[0][w*512]);
  gload16(Vt + (size_t)ts*4096 + w*512 + l*8, &Vl[0][w*512]);

  for (int t=ts; t<te; t++){
    int cur = (t-ts)&1;
    __syncthreads();
    if (t+1 < te){
      gload16(Kt + (size_t)(t+1)*4096 + w*512 + l*8, &Kl[cur^1][w*512]);
      gload16(Vt + (size_t)(t+1)*4096 + w*512 + l*8, &Vl[cur^1][w*512]);
    }
    f32x16 s0 = {}, s1 = {};
    __builtin_amdgcn_s_setprio(1);
    #pragma unroll
    for (int st=0;st<4;st++){
      bf16x8 kf0 = *(const bf16x8*)&Kl[cur][r0 + co[st]];
      bf16x8 kf1 = *(const bf16x8*)&Kl[cur][r1 + co[st]];
      s0 = __builtin_amdgcn_mfma_f32_32x32x16_bf16(kf0, qf[st], s0, 0,0,0);
      s1 = __builtin_amdgcn_mfma_f32_32x32x16_bf16(kf1, qf[st], s1, 0,0,0);
    }
    __builtin_amdgcn_s_setprio(0);
    float pm = -3e38f;
    #pragma unroll
    for (int r=0;r<16;r++) pm = fmaxf(fmaxf(pm, s0[r]), s1[r]);
    pm = fmaxf(pm, __shfl_xor(pm, 32));
    if (__any(pm > mrun + 8.f)){     // defer-max (T13): P bounded by 2^8
      float mn = fmaxf(mrun, pm);
      float sc = __builtin_amdgcn_exp2f(mrun - mn);
      mrun = mn;
      #pragma unroll
      for (int reg=0;reg<16;reg++){  // o rows are q=(reg&3)+8*(reg>>2)+4*hi
        float scr = __shfl(sc, (l & 32) | ((reg&3) + 8*(reg>>2) + 4*hi));
        o0[reg] *= scr;
        o1[reg] *= scr;
        osum[reg] *= scr;
      }
    }
    #pragma unroll
    for (int r=0;r<16;r++){
      s0[r] = __builtin_amdgcn_exp2f(s0[r] - mrun);
      s1[r] = __builtin_amdgcn_exp2f(s1[r] - mrun);
    }
    #define PV_STEP(SV, SGN, KVS)                                                    \
    {                                                                                \
      unsigned Aw = cvtpk(SV[SGN+0], SV[SGN+1]);                                     \
      unsigned Bw = cvtpk(SV[SGN+2], SV[SGN+3]);                                     \
      unsigned Cw = cvtpk(SV[SGN+4], SV[SGN+5]);                                     \
      unsigned Dw = cvtpk(SV[SGN+6], SV[SGN+7]);                                     \
      asm volatile("v_permlane32_swap_b32 %0, %1" : "+v"(Aw), "+v"(Cw));             \
      asm volatile("v_permlane32_swap_b32 %0, %1" : "+v"(Bw), "+v"(Dw));             \
      u32x4 pw = {Aw, Bw, Cw, Dw};                                                   \
      bf16x8 pa = *(const bf16x8*)&pw;                                               \
      bf16x8 vf0 = *(const bf16x8*)&Vl[cur][r0 + co[KVS]];                           \
      bf16x8 vf1 = *(const bf16x8*)&Vl[cur][r1 + co[KVS]];                           \
      __builtin_amdgcn_s_setprio(1);                                                 \
      o0 = __builtin_amdgcn_mfma_f32_32x32x16_bf16(pa, vf0, o0, 0,0,0);              \
      o1 = __builtin_amdgcn_mfma_f32_32x32x16_bf16(pa, vf1, o1, 0,0,0);              \
      osum = __builtin_amdgcn_mfma_f32_32x32x16_bf16(pa, vone, osum, 0,0,0);         \
      __builtin_amdgcn_s_setprio(0);                                                 \
    }
    PV_STEP(s0, 0, 0)
    PV_STEP(s0, 8, 1)
    PV_STEP(s1, 0, 2)
    PV_STEP(s1, 8, 3)
    #undef PV_STEP
  }
  size_t rbase = ((size_t)sp*NBH + bh)*SEQ;
  #pragma unroll
  for (int reg=0;reg<16;reg++){
    int q = q0w + (reg&3) + 8*(reg>>2) + 4*hi;
    Opart[(rbase + q)*64 + q5]      = f2bf(o0[reg]);
    Opart[(rbase + q)*64 + 32 + q5] = f2bf(o1[reg]);
  }
  if (l < 32)
    Mpart[rbase + q0w + l] = mrun;
  if (q5 == 0){
    #pragma unroll
    for (int reg=0;reg<16;reg++){
      int q = q0w + (reg&3) + 8*(reg>>2) + 4*hi;
      Spart[rbase + q] = osum[reg];
    }
  }
}

// ---------------- merge 4 kv-split partials (bf16 O) -> ao (bf16) ----------------
__global__ __launch_bounds__(256) void attn_merge(
    const bf16* __restrict__ Opart, const float* __restrict__ Mpart,
    const float* __restrict__ Spart, bf16* __restrict__ ao)
{
  int r = blockIdx.x*4 + (threadIdx.x>>6);   // global q-row id: bh*2048 + q
  int d = threadIdx.x & 63;
  float m0 = Mpart[r],            m1 = Mpart[NQROWS + r];
  float m2 = Mpart[2*NQROWS + r], m3 = Mpart[3*NQROWS + r];
  float m  = fmaxf(fmaxf(m0, m1), fmaxf(m2, m3));
  float c0 = exp2f(m0 - m), c1 = exp2f(m1 - m);
  float c2 = exp2f(m2 - m), c3 = exp2f(m3 - m);
  float denom = Spart[r]*c0 + Spart[NQROWS + r]*c1
              + Spart[2*NQROWS + r]*c2 + Spart[3*NQROWS + r]*c3;
  float v = __bfloat162float(Opart[(size_t)r*64 + d])*c0
          + __bfloat162float(Opart[((size_t)NQROWS + r)*64 + d])*c1
          + __bfloat162float(Opart[((size_t)2*NQROWS + r)*64 + d])*c2
          + __bfloat162float(Opart[((size_t)3*NQROWS + r)*64 + d])*c3;
  int bh = r >> 11, q = r & 2047;
  int b = bh >> 4, h = bh & 15;
  ao[((size_t)(b*SEQ + q))*DIM + h*DH + d] = f2bf(v / denom);
}

extern "C" void kernel_launch(void* const* d_in, const int* in_sizes, int n_in,
                              void* d_out, int out_size, void* d_ws, size_t ws_size,
                              hipStream_t stream)
{
  const float* x     = (const float*)d_in[0];
  const float* gamma = (const float*)d_in[1];
  const float* beta  = (const float*)d_in[2];
  const float* w_qkv = (const float*)d_in[3];
  const float* w_out = (const float*)d_in[4];
  const float* b_out = (const float*)d_in[5];
  float* out = (float*)d_out;

  bf16* ws  = (bf16*)d_ws;
  bf16* xn  = ws;                                  // 4096*1024
  bf16* wqt = xn  + (size_t)ROWS*DIM;              // 3072*1024
  bf16* wot = wqt + (size_t)NQKV*DIM;              // 1024*1024
  bf16* qb  = wot + (size_t)DIM*DIM;               // 32*2048*64
  bf16* kb  = qb  + (size_t)NBH*SEQ*DH;
  bf16* vtb = kb  + (size_t)NBH*SEQ*DH;
  bf16* ao  = vtb + (size_t)NBH*SEQ*DH;            // 4096*1024
  bf16* Opart = ao + (size_t)ROWS*DIM;             // 4*65536*64 bf16
  float* Mpart = (float*)(Opart + (size_t)NSPLIT*NQROWS*DH);
  float* Spart = Mpart + (size_t)NSPLIT*NQROWS;

  prep_kernel<<<dim3(ROWS + 768 + 256), dim3(256), 0, stream>>>(
      x, gamma, beta, xn, w_qkv, wqt, w_out, wot);
  gemm_bt<128><<<dim3(NQKV/128, ROWS/128), dim3(256), 0, stream>>>(
      xn, wqt, DIM, 0, qb, kb, vtb, (float*)nullptr, (const float*)nullptr);
  attn_part<<<dim3(SEQ/256, NBH, NSPLIT), dim3(512), 0, stream>>>(
      qb, kb, vtb, Opart, Mpart, Spart);
  attn_merge<<<dim3(NQROWS/4), dim3(256), 0, stream>>>(Opart, Mpart, Spart, ao);
  gemm_bt<64><<<dim3(DIM/64, ROWS/64), dim3(256), 0, stream>>>(
      ao, wot, DIM, 1, (bf16*)nullptr, (bf16*)nullptr, (bf16*)nullptr, out, b_out);
}

// Round 19
// 119.055 us; speedup vs baseline: 1.0540x; 1.0540x over previous
//
#include <hip/hip_runtime.h>
#include <hip/hip_bf16.h>

#define HEADS 16
#define DH 64
#define DIM 1024
#define SEQ 2048
#define BATCH 2
#define ROWS (BATCH*SEQ)      // 4096
#define NQKV (3*DIM)          // 3072
#define NKVT (SEQ/64)         // 32 kv tiles per bh
#define NSPLIT 2
#define QSCALE 0.18033688011112042f   // 0.125 * log2(e)
#define NBH (BATCH*HEADS)             // 32
#define NQROWS (NBH*SEQ)              // 65536

typedef __attribute__((ext_vector_type(8))) short bf16x8;
typedef __attribute__((ext_vector_type(4))) float f32x4;
typedef __attribute__((ext_vector_type(16))) float f32x16;
typedef __attribute__((ext_vector_type(4))) unsigned u32x4;
typedef __hip_bfloat16 bf16;

static __device__ __forceinline__ bf16 f2bf(float v){ return __float2bfloat16(v); }

// v_cvt_pk_bf16_f32: D.lo16 = bf16(S0), D.hi16 = bf16(S1)
static __device__ __forceinline__ unsigned cvtpk(float a, float b){
  unsigned r;
  asm("v_cvt_pk_bf16_f32 %0, %1, %2" : "=v"(r) : "v"(a), "v"(b));
  return r;
}

static __device__ __forceinline__ void gload16(const void* g, void* lds){
  __builtin_amdgcn_global_load_lds((const __attribute__((address_space(1))) void*)g,
                                   (__attribute__((address_space(3))) void*)lds, 16, 0, 0);
}

// ---------------- prep: LN (blocks 0..4095) + w_qkv^T (next 768) + w_out^T (next 256) --
__global__ __launch_bounds__(256) void prep_kernel(
    const float* __restrict__ x, const float* __restrict__ gamma,
    const float* __restrict__ beta, bf16* __restrict__ xn,
    const float* __restrict__ w_qkv, bf16* __restrict__ wqt,
    const float* __restrict__ w_out, bf16* __restrict__ wot)
{
  __shared__ float red[8];
  __shared__ __align__(16) bf16 tt[64][72];
  int bid = blockIdx.x;
  int tid = threadIdx.x;
  if (bid < ROWS){
    int row = bid;
    float4 v = ((const float4*)(x + (size_t)row*DIM))[tid];
    float s  = v.x+v.y+v.z+v.w;
    float ss = v.x*v.x+v.y*v.y+v.z*v.z+v.w*v.w;
    #pragma unroll
    for (int m=1;m<64;m<<=1){ s += __shfl_xor(s,m); ss += __shfl_xor(ss,m); }
    int wid = tid>>6;
    if ((tid&63)==0){ red[wid]=s; red[4+wid]=ss; }
    __syncthreads();
    s  = red[0]+red[1]+red[2]+red[3];
    ss = red[4]+red[5]+red[6]+red[7];
    float mu  = s*(1.0f/DIM);
    float var = ss*(1.0f/DIM) - mu*mu;
    float inv = rsqrtf(var + 1e-5f);
    float4 g  = ((const float4*)gamma)[tid];
    float4 bb = ((const float4*)beta)[tid];
    __align__(8) bf16 o[4];
    o[0]=f2bf((v.x-mu)*inv*g.x+bb.x);
    o[1]=f2bf((v.y-mu)*inv*g.y+bb.y);
    o[2]=f2bf((v.z-mu)*inv*g.z+bb.z);
    o[3]=f2bf((v.w-mu)*inv*g.w+bb.w);
    *(uint2*)&xn[(size_t)row*DIM + tid*4] = *(const uint2*)o;
    return;
  }
  const float* in; bf16* out; int R, C, bx, by;
  if (bid < ROWS + 768){
    int idx = bid - ROWS; bx = idx % 48; by = idx / 48;
    in = w_qkv; out = wqt; R = DIM; C = NQKV;
  } else {
    int idx = bid - ROWS - 768; bx = idx % 16; by = idx / 16;
    in = w_out; out = wot; R = DIM; C = DIM;
  }
  int c0 = bx*64, r0 = by*64;
  int row = tid>>2;
  int cq  = (tid&3)*16;
  #pragma unroll
  for (int j=0;j<4;j++){
    float4 v = *(const float4*)&in[(size_t)(r0+row)*C + c0 + cq + j*4];
    tt[cq+j*4+0][row] = f2bf(v.x);
    tt[cq+j*4+1][row] = f2bf(v.y);
    tt[cq+j*4+2][row] = f2bf(v.z);
    tt[cq+j*4+3][row] = f2bf(v.w);
  }
  __syncthreads();
  int c = tid>>2; int rq = (tid&3)*16;
  uint4 u0 = *(const uint4*)&tt[c][rq];
  uint4 u1 = *(const uint4*)&tt[c][rq+8];
  *(uint4*)&out[(size_t)(c0+c)*R + r0 + rq]     = u0;
  *(uint4*)&out[(size_t)(c0+c)*R + r0 + rq + 8] = u1;
}

// ---------------- GEMM v5: BK=32, 3-buffer counted-vmcnt pipeline, XCD swizzle -------
template<int BM>
__global__ __launch_bounds__(256) void gemm_bt(
    const bf16* __restrict__ A, const bf16* __restrict__ Bt, int K, int mode,
    bf16* __restrict__ qb, bf16* __restrict__ kb, bf16* __restrict__ vtb,
    float* __restrict__ outf, const float* __restrict__ bias)
{
  constexpr int MT = (BM == 128) ? 4 : 2;
  constexpr int NT = (BM == 128) ? 4 : 2;
  __shared__ __align__(16) bf16 aL[3][BM*32];
  __shared__ __align__(16) bf16 bL[3][BM*32];
  int tid = threadIdx.x;
  int w = tid>>6, l = tid&63;
  int lr = l&15, lh = l>>4;
  int wr = w>>1, wc = w&1;
  // XCD-aware bijective swizzle (grid %8 == 0)
  int nbx = gridDim.x;
  int lin = blockIdx.y*nbx + blockIdx.x;
  int cpx = (nbx*gridDim.y) >> 3;
  int nl  = (lin & 7)*cpx + (lin >> 3);
  int bx = nl % nbx, by = nl / nbx;
  const bf16* Ab = A  + (size_t)(by*BM)*K;
  const bf16* Bb = Bt + (size_t)(bx*BM)*K;
  int srow = w*32 + (l>>2);
  int scol = ((l&3)*8) ^ (((l>>2)&3)<<3);         // pre-swizzled global column
  int frsw = (lr&3)<<3;
  int nt = K/32;

  f32x4 acc[MT][NT] = {};

  auto STAGE = [&](int buf, int k0){
    if constexpr (BM == 128){
      gload16(Ab + (size_t)(srow   )*K + k0 + scol, &aL[buf][w*1024      ]);
      gload16(Ab + (size_t)(srow+16)*K + k0 + scol, &aL[buf][w*1024 + 512]);
      gload16(Bb + (size_t)(srow   )*K + k0 + scol, &bL[buf][w*1024      ]);
      gload16(Bb + (size_t)(srow+16)*K + k0 + scol, &bL[buf][w*1024 + 512]);
    } else {
      gload16(Ab + (size_t)(tid>>2)*K + k0 + scol, &aL[buf][w*512]);
      gload16(Bb + (size_t)(tid>>2)*K + k0 + scol, &bL[buf][w*512]);
    }
  };

  auto COMPUTE = [&](int buf){
    bf16x8 af[MT], bfr[NT];
    #pragma unroll
    for (int m=0;m<MT;m++)
      af[m]  = *(const bf16x8*)&aL[buf][(wr*(MT*16) + m*16 + lr)*32 + ((lh*8) ^ frsw)];
    #pragma unroll
    for (int n=0;n<NT;n++)
      bfr[n] = *(const bf16x8*)&bL[buf][(wc*(NT*16) + n*16 + lr)*32 + ((lh*8) ^ frsw)];
    #pragma unroll
    for (int m=0;m<MT;m++)
      #pragma unroll
      for (int n=0;n<NT;n++)
        acc[m][n] = __builtin_amdgcn_mfma_f32_16x16x32_bf16(af[m], bfr[n], acc[m][n], 0,0,0);
  };

  STAGE(0, 0);
  STAGE(1, 32);
  int cur = 0;
  for (int t=0; t<nt-1; t++){
    if constexpr (BM == 128) asm volatile("s_waitcnt vmcnt(4)" ::: "memory");
    else                     asm volatile("s_waitcnt vmcnt(2)" ::: "memory");
    __builtin_amdgcn_s_barrier();
    __builtin_amdgcn_sched_barrier(0);
    int s2 = cur + 2; if (s2 >= 3) s2 -= 3;
    if (t+2 < nt) STAGE(s2, (t+2)*32);
    COMPUTE(cur);
    cur = (cur == 2) ? 0 : cur + 1;
  }
  asm volatile("s_waitcnt vmcnt(0)" ::: "memory");
  __builtin_amdgcn_s_barrier();
  __builtin_amdgcn_sched_barrier(0);
  COMPUTE(cur);

  int rb = by*BM + wr*(MT*16), cb = bx*BM + wc*(NT*16);
  if (mode == 1){
    #pragma unroll
    for (int m=0;m<MT;m++)
      #pragma unroll
      for (int n=0;n<NT;n++)
        #pragma unroll
        for (int reg=0;reg<4;reg++){
          int r = rb + m*16 + lh*4 + reg;
          int c = cb + n*16 + lr;
          outf[(size_t)r*DIM + c] = acc[m][n][reg] + bias[c];
        }
  } else if (bx < 8){            // ---- Q: scaled (log2 domain), row-major [bh][n][d]
    int b = rb >> 11;
    int nn0 = rb & 2047;
    #pragma unroll
    for (int m=0;m<MT;m++)
      #pragma unroll
      for (int n=0;n<NT;n++)
        #pragma unroll
        for (int reg=0;reg<4;reg++){
          int nn = nn0 + m*16 + lh*4 + reg;
          int c  = cb + n*16 + lr;
          int hh = c >> 6, dd = c & 63;
          qb[((size_t)(b*HEADS + hh)*SEQ + nn)*DH + dd] = f2bf(acc[m][n][reg]*QSCALE);
        }
  } else if (bx < 16){           // ---- K: 64x64 tiles, swizzled in global
    int b = rb >> 11;
    int kvt = (rb & 2047) >> 6;
    int hh0 = ((cb - 1024) >> 6);
    #pragma unroll
    for (int m=0;m<MT;m++)
      #pragma unroll
      for (int reg=0;reg<4;reg++){
        int kvi = m*16 + lh*4 + reg;
        int sw  = (kvi&7)<<3;
        #pragma unroll
        for (int n=0;n<NT;n++){
          int dd = n*16 + lr;
          kb[((size_t)(b*HEADS + hh0)*NKVT + kvt)*4096 + kvi*64 + (dd ^ sw)] = f2bf(acc[m][n][reg]);
        }
      }
  } else {                       // ---- V: transpose in LDS, coalesced 16B stores
    __syncthreads();
    bf16* tl = (w < 2 ? (bf16*)aL : (bf16*)bL) + (w&1)*4096;
    int b   = rb >> 11;
    int kvt = (rb & 2047) >> 6;
    int hh  = (cb - 2048) >> 6;
    #pragma unroll
    for (int n=0;n<NT;n++){
      int dd = n*16 + lr;
      int sw = (dd&7)<<3;
      #pragma unroll
      for (int m=0;m<MT;m++)
        #pragma unroll
        for (int reg=0;reg<4;reg++)
          tl[dd*64 + ((m*16 + lh*4 + reg) ^ sw)] = f2bf(acc[m][n][reg]);
    }
    __syncthreads();
    size_t gb = ((size_t)(b*HEADS + hh)*NKVT + kvt)*4096;
    #pragma unroll
    for (int j=0;j<8;j++)
      *(uint4*)&vtb[gb + j*512 + l*8] = *(const uint4*)&tl[j*512 + l*8];
  }
}

// ---------------- flash attention v10: 8-wave blocks (256 q-rows), NSPLIT=2 ----------
// 32x32 MFMA, K/V dbuf, in-reg P via cvt_pk+permlane, ones-MFMA row-sum, XCD swizzle.
__global__ __launch_bounds__(512,4) void attn_part(
    const bf16* __restrict__ qb, const bf16* __restrict__ kb,
    const bf16* __restrict__ vtb,
    bf16* __restrict__ Opart, float* __restrict__ Mpart, float* __restrict__ Spart)
{
  __shared__ __align__(16) bf16 Kl[2][4096];
  __shared__ __align__(16) bf16 Vl[2][4096];
  int tid = threadIdx.x;
  int w = tid>>6, l = tid&63;      // w in 0..7
  int q5 = l & 31;
  int hi = l >> 5;
  int swz = (q5&7)<<3;
  // XCD swizzle: grid 8x32x2 = 512 blocks; each XCD owns 8 full (bh,sp) groups
  int lin = (blockIdx.z*gridDim.y + blockIdx.y)*gridDim.x + blockIdx.x;
  int nl  = (lin & 7)*64 + (lin >> 3);
  int bqx = nl & 7;
  int bh  = (nl >> 3) & 31;
  int sp  = nl >> 8;
  int ts = sp*16, te = ts+16;
  const bf16* Q  = qb  + (size_t)bh*SEQ*DH;
  const bf16* Kt = kb  + (size_t)bh*NKVT*4096;
  const bf16* Vt = vtb + (size_t)bh*NKVT*4096;
  int q0w = bqx*256 + w*32;   // this wave's 32 Q rows

  int co[4];
  #pragma unroll
  for (int st=0;st<4;st++) co[st] = (st*16 + hi*8) ^ swz;
  int r0 = q5*64, r1 = r0 + 2048;

  bf16x8 qf[4];
  #pragma unroll
  for (int st=0;st<4;st++)
    qf[st] = *(const bf16x8*)&Q[(size_t)(q0w + q5)*DH + st*16 + hi*8];

  bf16x8 vone;
  #pragma unroll
  for (int i=0;i<8;i++) vone[i] = (short)0x3f80;   // bf16 1.0

  f32x16 o0 = {}, o1 = {}, osum = {};  // d-tiles 0/1 and the ones-column row-sum
  float mrun = -3e38f;

  // prologue: 8 waves cooperatively stage tile ts (1 K-load + 1 V-load per wave)
  gload16(Kt + (size_t)ts*4096 + w*512 + l*8, &Kl[0][w*512]);
  gload16(Vt + (size_t)ts*4096 + w*512 + l*8, &Vl[0][w*512]);

  for (int t=ts; t<te; t++){
    int cur = (t-ts)&1;
    __syncthreads();
    if (t+1 < te){
      gload16(Kt + (size_t)(t+1)*4096 + w*512 + l*8, &Kl[cur^1][w*512]);
      gload16(Vt + (size_t)(t+1)*4096 + w*512 + l*8, &Vl[cur^1][w*512]);
    }
    f32x16 s0 = {}, s1 = {};
    __builtin_amdgcn_s_setprio(1);
    #pragma unroll
    for (int st=0;st<4;st++){
      bf16x8 kf0 = *(const bf16x8*)&Kl[cur][r0 + co[st]];
      bf16x8 kf1 = *(const bf16x8*)&Kl[cur][r1 + co[st]];
      s0 = __builtin_amdgcn_mfma_f32_32x32x16_bf16(kf0, qf[st], s0, 0,0,0);
      s1 = __builtin_amdgcn_mfma_f32_32x32x16_bf16(kf1, qf[st], s1, 0,0,0);
    }
    __builtin_amdgcn_s_setprio(0);
    float pm = -3e38f;
    #pragma unroll
    for (int r=0;r<16;r++) pm = fmaxf(fmaxf(pm, s0[r]), s1[r]);
    pm = fmaxf(pm, __shfl_xor(pm, 32));
    if (__any(pm > mrun + 8.f)){     // defer-max (T13): P bounded by 2^8
      float mn = fmaxf(mrun, pm);
      float sc = __builtin_amdgcn_exp2f(mrun - mn);
      mrun = mn;
      #pragma unroll
      for (int reg=0;reg<16;reg++){  // o rows are q=(reg&3)+8*(reg>>2)+4*hi
        float scr = __shfl(sc, (l & 32) | ((reg&3) + 8*(reg>>2) + 4*hi));
        o0[reg] *= scr;
        o1[reg] *= scr;
        osum[reg] *= scr;
      }
    }
    #pragma unroll
    for (int r=0;r<16;r++){
      s0[r] = __builtin_amdgcn_exp2f(s0[r] - mrun);
      s1[r] = __builtin_amdgcn_exp2f(s1[r] - mrun);
    }
    #define PV_STEP(SV, SGN, KVS)                                                    \
    {                                                                                \
      unsigned Aw = cvtpk(SV[SGN+0], SV[SGN+1]);                                     \
      unsigned Bw = cvtpk(SV[SGN+2], SV[SGN+3]);                                     \
      unsigned Cw = cvtpk(SV[SGN+4], SV[SGN+5]);                                     \
      unsigned Dw = cvtpk(SV[SGN+6], SV[SGN+7]);                                     \
      asm volatile("v_permlane32_swap_b32 %0, %1" : "+v"(Aw), "+v"(Cw));             \
      asm volatile("v_permlane32_swap_b32 %0, %1" : "+v"(Bw), "+v"(Dw));             \
      u32x4 pw = {Aw, Bw, Cw, Dw};                                                   \
      bf16x8 pa = *(const bf16x8*)&pw;                                               \
      bf16x8 vf0 = *(const bf16x8*)&Vl[cur][r0 + co[KVS]];                           \
      bf16x8 vf1 = *(const bf16x8*)&Vl[cur][r1 + co[KVS]];                           \
      __builtin_amdgcn_s_setprio(1);                                                 \
      o0 = __builtin_amdgcn_mfma_f32_32x32x16_bf16(pa, vf0, o0, 0,0,0);              \
      o1 = __builtin_amdgcn_mfma_f32_32x32x16_bf16(pa, vf1, o1, 0,0,0);              \
      osum = __builtin_amdgcn_mfma_f32_32x32x16_bf16(pa, vone, osum, 0,0,0);         \
      __builtin_amdgcn_s_setprio(0);                                                 \
    }
    PV_STEP(s0, 0, 0)
    PV_STEP(s0, 8, 1)
    PV_STEP(s1, 0, 2)
    PV_STEP(s1, 8, 3)
    #undef PV_STEP
  }
  size_t rbase = ((size_t)sp*NBH + bh)*SEQ;
  #pragma unroll
  for (int reg=0;reg<16;reg++){
    int q = q0w + (reg&3) + 8*(reg>>2) + 4*hi;
    Opart[(rbase + q)*64 + q5]      = f2bf(o0[reg]);
    Opart[(rbase + q)*64 + 32 + q5] = f2bf(o1[reg]);
  }
  if (l < 32)
    Mpart[rbase + q0w + l] = mrun;
  if (q5 == 0){
    #pragma unroll
    for (int reg=0;reg<16;reg++){
      int q = q0w + (reg&3) + 8*(reg>>2) + 4*hi;
      Spart[rbase + q] = osum[reg];
    }
  }
}

// ---------------- merge 2 kv-split partials (bf16 O) -> ao (bf16) ----------------
__global__ __launch_bounds__(256) void attn_merge(
    const bf16* __restrict__ Opart, const float* __restrict__ Mpart,
    const float* __restrict__ Spart, bf16* __restrict__ ao)
{
  int r = blockIdx.x*4 + (threadIdx.x>>6);   // global q-row id: bh*2048 + q
  int d = threadIdx.x & 63;
  float m0 = Mpart[r], m1 = Mpart[NQROWS + r];
  float m  = fmaxf(m0, m1);
  float c0 = exp2f(m0 - m), c1 = exp2f(m1 - m);
  float denom = Spart[r]*c0 + Spart[NQROWS + r]*c1;
  float v = __bfloat162float(Opart[(size_t)r*64 + d])*c0
          + __bfloat162float(Opart[((size_t)NQROWS + r)*64 + d])*c1;
  int bh = r >> 11, q = r & 2047;
  int b = bh >> 4, h = bh & 15;
  ao[((size_t)(b*SEQ + q))*DIM + h*DH + d] = f2bf(v / denom);
}

extern "C" void kernel_launch(void* const* d_in, const int* in_sizes, int n_in,
                              void* d_out, int out_size, void* d_ws, size_t ws_size,
                              hipStream_t stream)
{
  const float* x     = (const float*)d_in[0];
  const float* gamma = (const float*)d_in[1];
  const float* beta  = (const float*)d_in[2];
  const float* w_qkv = (const float*)d_in[3];
  const float* w_out = (const float*)d_in[4];
  const float* b_out = (const float*)d_in[5];
  float* out = (float*)d_out;

  bf16* ws  = (bf16*)d_ws;
  bf16* xn  = ws;                                  // 4096*1024
  bf16* wqt = xn  + (size_t)ROWS*DIM;              // 3072*1024
  bf16* wot = wqt + (size_t)NQKV*DIM;              // 1024*1024
  bf16* qb  = wot + (size_t)DIM*DIM;               // 32*2048*64
  bf16* kb  = qb  + (size_t)NBH*SEQ*DH;
  bf16* vtb = kb  + (size_t)NBH*SEQ*DH;
  bf16* ao  = vtb + (size_t)NBH*SEQ*DH;            // 4096*1024
  bf16* Opart = ao + (size_t)ROWS*DIM;             // 2*65536*64 bf16
  float* Mpart = (float*)(Opart + (size_t)NSPLIT*NQROWS*DH);
  float* Spart = Mpart + (size_t)NSPLIT*NQROWS;

  prep_kernel<<<dim3(ROWS + 768 + 256), dim3(256), 0, stream>>>(
      x, gamma, beta, xn, w_qkv, wqt, w_out, wot);
  gemm_bt<128><<<dim3(NQKV/128, ROWS/128), dim3(256), 0, stream>>>(
      xn, wqt, DIM, 0, qb, kb, vtb, (float*)nullptr, (const float*)nullptr);
  attn_part<<<dim3(SEQ/256, NBH, NSPLIT), dim3(512), 0, stream>>>(
      qb, kb, vtb, Opart, Mpart, Spart);
  attn_merge<<<dim3(NQROWS/4), dim3(256), 0, stream>>>(Opart, Mpart, Spart, ao);
  gemm_bt<64><<<dim3(DIM/64, ROWS/64), dim3(256), 0, stream>>>(
      ao, wot, DIM, 1, (bf16*)nullptr, (bf16*)nullptr, (bf16*)nullptr, out, b_out);
}